// Round 5
// baseline (6627.036 us; speedup 1.0000x reference)
//
#include <hip/hip_runtime.h>
#include <math.h>

// RNN: L=512, B=128, D=512, H=1024, fp32 in/out.
//   xproj = x @ Wx^T + bx   (65536x1024x512 GEMM) -> written into d_out
//   h_t = tanh(xp_t + h_{t-1} @ Wh^T), in-place over d_out slices.
// Precision: split-bf16 (hi+lo) operands, 3 MFMAs per product => ~fp32 accuracy.
// Round 5 changes (persistent kernel):
//  (1) Wh fragments hoisted into registers ONCE (constant across 512 steps).
//  (2) A-loads fully unrolled: 32x 8B sc0sc1 loads burst-issued (round 4 had
//      VGPR_Count=28 -> 4 serialized L3 round-trips; now one ~900cy burst).
//  (3) Full 64-WG group barrier replaced by per-(mb,kchunk) dataflow counters:
//      wave q only needs h cols [128q,+128) = the 8 WGs with nb>>3==q.

#define L_SEQ 512
#define B_SZ  128
#define D_SZ  512
#define H_SZ  1024
#define BH    (B_SZ * H_SZ)   // 131072

typedef __bf16 bf16x8 __attribute__((ext_vector_type(8)));
typedef float  f32x4  __attribute__((ext_vector_type(4)));

union V8 { bf16x8 b; unsigned short u[8]; };

__device__ __forceinline__ unsigned short f2bf(float f) {
  unsigned int u = __float_as_uint(f);
  u += 0x7FFFu + ((u >> 16) & 1u);   // round-to-nearest-even
  return (unsigned short)(u >> 16);
}
__device__ __forceinline__ float bf2f(unsigned short s) {
  return __uint_as_float(((unsigned int)s) << 16);
}

// 16B fragment as two 8B agent-scope relaxed loads (sc0 sc1: bypass L1/L2,
// read the L3 coherence point -> always-fresh h state, no cache fences).
__device__ __forceinline__ bf16x8 ld_hb16(const unsigned short* p) {
  union { bf16x8 v; unsigned long long q[2]; } u;
  u.q[0] = __hip_atomic_load((const unsigned long long*)p,
                             __ATOMIC_RELAXED, __HIP_MEMORY_SCOPE_AGENT);
  u.q[1] = __hip_atomic_load((const unsigned long long*)(p + 4),
                             __ATOMIC_RELAXED, __HIP_MEMORY_SCOPE_AGENT);
  return u.v;
}

// ---- d_ws layout (ushort elements unless noted) ----
#define WS_WHH 0            // [1024][1024]
#define WS_WHL 1048576      // [1024][1024]
#define WS_WXH 2097152      // [1024][512]
#define WS_WXL 2621440      // [1024][512]
#define WS_HB  3145728      // [2 parity][2 hi/lo][BH]
#define WS_CNT 3670016      // 32 counters x 16-uint stride (2 KB)

// Split fp32 weights into bf16 hi + bf16 lo(residual); zero dataflow counters.
__global__ void split_kernel(const float* __restrict__ Wh,
                             const float* __restrict__ Wx,
                             unsigned short* __restrict__ ws,
                             unsigned int* __restrict__ cnt) {
  if (blockIdx.x == 0) {
    for (int i = threadIdx.x; i < 512; i += 256) cnt[i] = 0u;
  }
  const int total = 1048576 + 524288;
  for (int i = blockIdx.x * blockDim.x + threadIdx.x; i < total;
       i += gridDim.x * blockDim.x) {
    const float* src; unsigned short *dh, *dl; int j;
    if (i < 1048576) { src = Wh; dh = ws + WS_WHH; dl = ws + WS_WHL; j = i; }
    else             { src = Wx; dh = ws + WS_WXH; dl = ws + WS_WXL; j = i - 1048576; }
    float v = src[j];
    unsigned short h = f2bf(v);
    dh[j] = h;
    dl[j] = f2bf(v - bf2f(h));
  }
}

// xproj: out[m][n] = sum_d x[m][d]*Wx[n][d] + bx[n]  (unchanged)
__global__ __launch_bounds__(256) void xproj_kernel(
    const float* __restrict__ x,             // [65536][512]
    const unsigned short* __restrict__ wxh,  // [1024][512]
    const unsigned short* __restrict__ wxl,
    const float* __restrict__ bx,            // [1024]
    float* __restrict__ out)                 // [65536][1024]
{
  const int bid = blockIdx.x;
  const int bn = bid & 15;
  const int bm = bid >> 4;
  const int tid = threadIdx.x;
  const int w = tid >> 6, l = tid & 63;
  const int wm = w & 1, wn = w >> 1;
  const int lr = l & 15, lk = (l >> 4) * 8;
  const int mbase = bm * 128 + wm * 64;
  const int nbase = bn * 64 + wn * 32;

  f32x4 acc[4][2] = {};

  for (int k0 = 0; k0 < 512; k0 += 32) {
    bf16x8 ah[4], al[4], bh[2], bl[2];
#pragma unroll
    for (int i = 0; i < 4; ++i) {
      const float* ap = x + (size_t)(mbase + i * 16 + lr) * 512 + k0 + lk;
      float4 v0 = *reinterpret_cast<const float4*>(ap);
      float4 v1 = *reinterpret_cast<const float4*>(ap + 4);
      float vv[8] = {v0.x, v0.y, v0.z, v0.w, v1.x, v1.y, v1.z, v1.w};
      V8 hh, ll;
#pragma unroll
      for (int e = 0; e < 8; ++e) {
        unsigned short hb = f2bf(vv[e]);
        hh.u[e] = hb;
        ll.u[e] = f2bf(vv[e] - bf2f(hb));
      }
      ah[i] = hh.b; al[i] = ll.b;
    }
#pragma unroll
    for (int j = 0; j < 2; ++j) {
      size_t boff = (size_t)(nbase + j * 16 + lr) * 512 + k0 + lk;
      bh[j] = *reinterpret_cast<const bf16x8*>(wxh + boff);
      bl[j] = *reinterpret_cast<const bf16x8*>(wxl + boff);
    }
#pragma unroll
    for (int i = 0; i < 4; ++i)
#pragma unroll
      for (int j = 0; j < 2; ++j) {
        acc[i][j] = __builtin_amdgcn_mfma_f32_16x16x32_bf16(ah[i], bh[j], acc[i][j], 0, 0, 0);
        acc[i][j] = __builtin_amdgcn_mfma_f32_16x16x32_bf16(ah[i], bl[j], acc[i][j], 0, 0, 0);
        acc[i][j] = __builtin_amdgcn_mfma_f32_16x16x32_bf16(al[i], bh[j], acc[i][j], 0, 0, 0);
      }
  }

#pragma unroll
  for (int j = 0; j < 2; ++j) {
    int n = nbase + j * 16 + lr;
    float bxv = bx[n];
#pragma unroll
    for (int i = 0; i < 4; ++i)
#pragma unroll
      for (int r = 0; r < 4; ++r) {
        int m = mbase + i * 16 + (l >> 4) * 4 + r;
        out[(size_t)m * 1024 + n] = acc[i][j][r] + bxv;
      }
  }
}

// Persistent recurrence (fence-free, dataflow-gated). 256 WGs x 512 threads.
// WG (mb,nb): output tile rows [mb*32,+32) x cols [nb*16,+16), all 512 steps.
// Wave q owns K-slice [q*128,+128). Wh frags live in registers for the whole
// kernel. Gate: wave q at step t waits cnt[mb][q] >= 8*t (its 8 producers).
// Safety vs ping-pong overwrite: a WG writes h_t only after ALL its waves
// passed their step-t gates (LDS-reduction __syncthreads enforces this), so
// when any WG reaches step t+2 (same parity plane as t), every WG of the
// group has finished step t+1, i.e. no one still reads h_t.
__global__ __launch_bounds__(512, 2) void rnn_persistent(
    const unsigned short* __restrict__ whh,  // [1024][1024]
    const unsigned short* __restrict__ whl,
    unsigned short* __restrict__ hb,         // [2][2][BH]
    float* __restrict__ out,                 // [512][BH] (xproj in, h out)
    unsigned int* __restrict__ cnt)          // [32][16] padded counters
{
  __shared__ float lds[8 * 32 * 17];         // 17408 B, stride-17 pad
  const int wg = blockIdx.x;                 // 0..255
  const int xc = wg & 7, yy = wg >> 3;
  const int mb = xc & 3;
  const int nb = ((xc >> 2) << 5) + yy;      // 0..63
  const int tid = threadIdx.x;
  const int q = tid >> 6;                    // k-slice 0..7
  const int l = tid & 63;
  const int lr = l & 15, lk = (l >> 4) * 8;
  const int kbase = q * 128 + lk;
  const int row0 = (l >> 4) * 4;

  // Wh fragments: constant across all steps -> registers (8 frags = 32 VGPRs).
  const unsigned short* bph = whh + (size_t)(nb * 16 + lr) * 1024 + kbase;
  const unsigned short* bpl = whl + (size_t)(nb * 16 + lr) * 1024 + kbase;
  bf16x8 vBh[4], vBl[4];
#pragma unroll
  for (int kb = 0; kb < 4; ++kb) {
    vBh[kb] = *reinterpret_cast<const bf16x8*>(bph + kb * 32);
    vBl[kb] = *reinterpret_cast<const bf16x8*>(bpl + kb * 32);
  }

  const size_t aoff = (size_t)(mb * 32 + lr) * 1024 + kbase;

  // Epilogue mapping: one output element per thread.
  const int em = tid >> 4, en = tid & 15;
  const size_t eidx = (size_t)(mb * 32 + em) * 1024 + nb * 16 + en;

  unsigned int* my_arrive = cnt + (mb * 8 + (nb >> 3)) * 16;
  unsigned int* my_gate   = cnt + (mb * 8 + q) * 16;

  for (int t = 0; t < L_SEQ; ++t) {
    float* xpt = out + (size_t)t * BH;
    const float xpv = xpt[eidx];             // thread-private, prefetch early
    float hval;

    if (t > 0) {
      // Dataflow gate: wait for this wave's 8 producer WGs from step t-1.
      if (l == 0) {
        const unsigned int tgt = 8u * (unsigned int)t;
        while (__hip_atomic_load(my_gate, __ATOMIC_RELAXED,
                                 __HIP_MEMORY_SCOPE_AGENT) < tgt) {
          __builtin_amdgcn_s_sleep(1);
        }
      }
      // wave reconverges; A-loads issue after the spin's final load resolves.

      const unsigned short* hh = hb + (size_t)(((t - 1) & 1) * 2) * BH;
      const unsigned short* hl = hh + BH;
      const unsigned short* a0h = hh + aoff;
      const unsigned short* a0l = hl + aoff;
      const unsigned short* a1h = a0h + 16 * 1024;
      const unsigned short* a1l = a0l + 16 * 1024;

      // Burst-load ALL A fragments (32 x 8B sc0sc1 loads in flight).
      bf16x8 vA0h[4], vA0l[4], vA1h[4], vA1l[4];
#pragma unroll
      for (int kb = 0; kb < 4; ++kb) {
        const int ko = kb * 32;
        vA0h[kb] = ld_hb16(a0h + ko);
        vA0l[kb] = ld_hb16(a0l + ko);
        vA1h[kb] = ld_hb16(a1h + ko);
        vA1l[kb] = ld_hb16(a1l + ko);
      }

      f32x4 acc0 = {0.f, 0.f, 0.f, 0.f};
      f32x4 acc1 = {0.f, 0.f, 0.f, 0.f};
#pragma unroll
      for (int kb = 0; kb < 4; ++kb) {
        acc0 = __builtin_amdgcn_mfma_f32_16x16x32_bf16(vA0h[kb], vBh[kb], acc0, 0, 0, 0);
        acc1 = __builtin_amdgcn_mfma_f32_16x16x32_bf16(vA1h[kb], vBh[kb], acc1, 0, 0, 0);
        acc0 = __builtin_amdgcn_mfma_f32_16x16x32_bf16(vA0h[kb], vBl[kb], acc0, 0, 0, 0);
        acc1 = __builtin_amdgcn_mfma_f32_16x16x32_bf16(vA1h[kb], vBl[kb], acc1, 0, 0, 0);
        acc0 = __builtin_amdgcn_mfma_f32_16x16x32_bf16(vA0l[kb], vBh[kb], acc0, 0, 0, 0);
        acc1 = __builtin_amdgcn_mfma_f32_16x16x32_bf16(vA1l[kb], vBh[kb], acc1, 0, 0, 0);
      }

      // Partials -> LDS. C/D layout: col = lane&15, row = (lane>>4)*4 + r.
#pragma unroll
      for (int r = 0; r < 4; ++r) {
        lds[q * 544 + (row0 + r) * 17 + lr]      = acc0[r];
        lds[q * 544 + (16 + row0 + r) * 17 + lr] = acc1[r];
      }
      __syncthreads();   // all waves' partials in LDS (=> all gates passed)

      float s = 0.f;
#pragma unroll
      for (int qq = 0; qq < 8; ++qq) s += lds[qq * 544 + em * 17 + en];
      hval = tanhf(s + xpv);
    } else {
      hval = tanhf(xpv);
    }

    // fp32 h in place (thread-private, ordinary cached store).
    xpt[eidx] = hval;
    // bf16 hi/lo state: agent-scope relaxed stores (write-through to L3).
    unsigned short hhi = f2bf(hval);
    unsigned short hlo = f2bf(hval - bf2f(hhi));
    unsigned short* hcur = hb + (size_t)((t & 1) * 2) * BH;
    __hip_atomic_store(hcur + eidx, hhi, __ATOMIC_RELAXED,
                       __HIP_MEMORY_SCOPE_AGENT);
    __hip_atomic_store(hcur + BH + eidx, hlo, __ATOMIC_RELAXED,
                       __HIP_MEMORY_SCOPE_AGENT);

    // Barrier drains each wave's vmcnt -> all h-stores acked at L3; also
    // protects LDS against next step's overwrite. Then publish arrival.
    __syncthreads();
    if (tid == 0) {
      __hip_atomic_fetch_add(my_arrive, 1u, __ATOMIC_RELAXED,
                             __HIP_MEMORY_SCOPE_AGENT);
    }
  }
}

extern "C" void kernel_launch(void* const* d_in, const int* in_sizes, int n_in,
                              void* d_out, int out_size, void* d_ws, size_t ws_size,
                              hipStream_t stream) {
  const float* x  = (const float*)d_in[0];   // [512][128][512]
  const float* Wx = (const float*)d_in[1];   // [1024][512]
  const float* bx = (const float*)d_in[2];   // [1024]
  const float* Wh = (const float*)d_in[3];   // [1024][1024]
  float* out = (float*)d_out;                // [512][128][1024]
  unsigned short* ws = (unsigned short*)d_ws;

  unsigned short* whh = ws + WS_WHH;
  unsigned short* whl = ws + WS_WHL;
  unsigned short* wxh = ws + WS_WXH;
  unsigned short* wxl = ws + WS_WXL;
  unsigned short* hb  = ws + WS_HB;          // [2][2][BH]
  unsigned int*   cnt = (unsigned int*)(ws + WS_CNT);

  split_kernel<<<dim3(2048), dim3(256), 0, stream>>>(Wh, Wx, ws, cnt);
  xproj_kernel<<<dim3(8192), dim3(256), 0, stream>>>(x, wxh, wxl, bx, out);
  rnn_persistent<<<dim3(256), dim3(512), 0, stream>>>(whh, whl, hb, out, cnt);
}

// Round 6
// 4638.600 us; speedup vs baseline: 1.4287x; 1.4287x over previous
//
#include <hip/hip_runtime.h>
#include <math.h>

// RNN: L=512, B=128, D=512, H=1024, fp32 in/out.
//   xproj = x @ Wx^T + bx   (65536x1024x512 GEMM) -> written into d_out
//   h_t = tanh(xp_t + h_{t-1} @ Wh^T), in-place over d_out slices.
// Precision: split-bf16 (hi+lo) operands, 3 MFMAs per product => ~fp32 accuracy.
// Round 6: R5's VGPR=40 proved __hip_atomic_load A-fetches were serialized
// (each atomic gets its own waitcnt -> 32 x ~700cy = the whole 11.6us/step).
// Fix: h-state packed as u32 (bf16hi | bf16lo<<16), fetched with inline-asm
// global_load_dwordx4 sc0 sc1 burst (16 loads in flight, ONE vmcnt(0)),
// sched_barrier(0) fence per rule #18. Producer stores 1 u32/element via
// inline-asm global_store_dword sc0 sc1; explicit vmcnt(0) drain before the
// arrival counter add preserves the release ordering.

#define L_SEQ 512
#define B_SZ  128
#define D_SZ  512
#define H_SZ  1024
#define BH    (B_SZ * H_SZ)   // 131072

typedef __bf16 bf16x8 __attribute__((ext_vector_type(8)));
typedef float  f32x4  __attribute__((ext_vector_type(4)));
typedef unsigned int uint;
typedef uint u32x4 __attribute__((ext_vector_type(4)));

union V8 { bf16x8 b; unsigned short u[8]; uint w[4]; };

__device__ __forceinline__ unsigned short f2bf(float f) {
  unsigned int u = __float_as_uint(f);
  u += 0x7FFFu + ((u >> 16) & 1u);   // round-to-nearest-even
  return (unsigned short)(u >> 16);
}
__device__ __forceinline__ float bf2f(unsigned short s) {
  return __uint_as_float(((unsigned int)s) << 16);
}

// 16B L1/L2-bypass load (reads L3 coherence point). Plain load, NOT atomic:
// the backend can keep many in flight; we drain with one vmcnt(0).
__device__ __forceinline__ void ldg16_sc(u32x4& d, const uint* p) {
  asm volatile("global_load_dwordx4 %0, %1, off sc0 sc1"
               : "=v"(d) : "v"(p) : "memory");
}
// 4B write-through store to the L3 coherence point.
__device__ __forceinline__ void stg4_sc(uint* p, uint v) {
  asm volatile("global_store_dword %0, %1, off sc0 sc1"
               :: "v"(p), "v"(v) : "memory");
}

// ---- d_ws layout (ushort elements unless noted) ----
#define WS_WHH 0            // [1024][1024]
#define WS_WHL 1048576      // [1024][1024]
#define WS_WXH 2097152      // [1024][512]
#define WS_WXL 2621440      // [1024][512]
#define WS_HB  3145728      // u32 [2 parity][BH] packed (hi | lo<<16), 1 MB
#define WS_CNT 3670016      // 32 counters x 16-uint stride (2 KB)

// Split fp32 weights into bf16 hi + bf16 lo(residual); zero dataflow counters.
__global__ void split_kernel(const float* __restrict__ Wh,
                             const float* __restrict__ Wx,
                             unsigned short* __restrict__ ws,
                             unsigned int* __restrict__ cnt) {
  if (blockIdx.x == 0) {
    for (int i = threadIdx.x; i < 512; i += 256) cnt[i] = 0u;
  }
  const int total = 1048576 + 524288;
  for (int i = blockIdx.x * blockDim.x + threadIdx.x; i < total;
       i += gridDim.x * blockDim.x) {
    const float* src; unsigned short *dh, *dl; int j;
    if (i < 1048576) { src = Wh; dh = ws + WS_WHH; dl = ws + WS_WHL; j = i; }
    else             { src = Wx; dh = ws + WS_WXH; dl = ws + WS_WXL; j = i - 1048576; }
    float v = src[j];
    unsigned short h = f2bf(v);
    dh[j] = h;
    dl[j] = f2bf(v - bf2f(h));
  }
}

// xproj: out[m][n] = sum_d x[m][d]*Wx[n][d] + bx[n]  (unchanged)
__global__ __launch_bounds__(256) void xproj_kernel(
    const float* __restrict__ x,             // [65536][512]
    const unsigned short* __restrict__ wxh,  // [1024][512]
    const unsigned short* __restrict__ wxl,
    const float* __restrict__ bx,            // [1024]
    float* __restrict__ out)                 // [65536][1024]
{
  const int bid = blockIdx.x;
  const int bn = bid & 15;
  const int bm = bid >> 4;
  const int tid = threadIdx.x;
  const int w = tid >> 6, l = tid & 63;
  const int wm = w & 1, wn = w >> 1;
  const int lr = l & 15, lk = (l >> 4) * 8;
  const int mbase = bm * 128 + wm * 64;
  const int nbase = bn * 64 + wn * 32;

  f32x4 acc[4][2] = {};

  for (int k0 = 0; k0 < 512; k0 += 32) {
    bf16x8 ah[4], al[4], bh[2], bl[2];
#pragma unroll
    for (int i = 0; i < 4; ++i) {
      const float* ap = x + (size_t)(mbase + i * 16 + lr) * 512 + k0 + lk;
      float4 v0 = *reinterpret_cast<const float4*>(ap);
      float4 v1 = *reinterpret_cast<const float4*>(ap + 4);
      float vv[8] = {v0.x, v0.y, v0.z, v0.w, v1.x, v1.y, v1.z, v1.w};
      V8 hh, ll;
#pragma unroll
      for (int e = 0; e < 8; ++e) {
        unsigned short hb = f2bf(vv[e]);
        hh.u[e] = hb;
        ll.u[e] = f2bf(vv[e] - bf2f(hb));
      }
      ah[i] = hh.b; al[i] = ll.b;
    }
#pragma unroll
    for (int j = 0; j < 2; ++j) {
      size_t boff = (size_t)(nbase + j * 16 + lr) * 512 + k0 + lk;
      bh[j] = *reinterpret_cast<const bf16x8*>(wxh + boff);
      bl[j] = *reinterpret_cast<const bf16x8*>(wxl + boff);
    }
#pragma unroll
    for (int i = 0; i < 4; ++i)
#pragma unroll
      for (int j = 0; j < 2; ++j) {
        acc[i][j] = __builtin_amdgcn_mfma_f32_16x16x32_bf16(ah[i], bh[j], acc[i][j], 0, 0, 0);
        acc[i][j] = __builtin_amdgcn_mfma_f32_16x16x32_bf16(ah[i], bl[j], acc[i][j], 0, 0, 0);
        acc[i][j] = __builtin_amdgcn_mfma_f32_16x16x32_bf16(al[i], bh[j], acc[i][j], 0, 0, 0);
      }
  }

#pragma unroll
  for (int j = 0; j < 2; ++j) {
    int n = nbase + j * 16 + lr;
    float bxv = bx[n];
#pragma unroll
    for (int i = 0; i < 4; ++i)
#pragma unroll
      for (int r = 0; r < 4; ++r) {
        int m = mbase + i * 16 + (l >> 4) * 4 + r;
        out[(size_t)m * 1024 + n] = acc[i][j][r] + bxv;
      }
  }
}

// Persistent recurrence (fence-free, dataflow-gated). 256 WGs x 512 threads.
// WG (mb,nb): rows [mb*32,+32) x cols [nb*16,+16), all 512 steps.
// Wave q owns K-slice [q*128,+128); Wh frags live in registers throughout.
// Gate: wave q at step t waits cnt[mb][q] >= 8*t (its 8 producer WGs).
// Safety vs ping-pong overwrite: a WG writes h_t only after ALL its waves
// passed their step-t gates (LDS __syncthreads enforces), so nobody can be
// two steps ahead of a peer -> parity plane reuse is race-free.
__global__ __launch_bounds__(512, 2) void rnn_persistent(
    const unsigned short* __restrict__ whh,  // [1024][1024]
    const unsigned short* __restrict__ whl,
    uint* __restrict__ hb32,                 // [2][BH] packed hi|lo<<16
    float* __restrict__ out,                 // [512][BH] (xproj in, h out)
    unsigned int* __restrict__ cnt)          // [32][16] padded counters
{
  __shared__ float lds[8 * 32 * 17];         // 17408 B, stride-17 pad
  const int wg = blockIdx.x;                 // 0..255
  const int xc = wg & 7, yy = wg >> 3;
  const int mb = xc & 3;
  const int nb = ((xc >> 2) << 5) + yy;      // 0..63
  const int tid = threadIdx.x;
  const int q = tid >> 6;                    // k-slice 0..7
  const int l = tid & 63;
  const int lr = l & 15, lk = (l >> 4) * 8;
  const int kbase = q * 128 + lk;
  const int row0 = (l >> 4) * 4;

  // Wh fragments: constant across all steps -> registers (8 frags = 32 VGPRs).
  const unsigned short* bph = whh + (size_t)(nb * 16 + lr) * 1024 + kbase;
  const unsigned short* bpl = whl + (size_t)(nb * 16 + lr) * 1024 + kbase;
  bf16x8 vBh[4], vBl[4];
#pragma unroll
  for (int kb = 0; kb < 4; ++kb) {
    vBh[kb] = *reinterpret_cast<const bf16x8*>(bph + kb * 32);
    vBl[kb] = *reinterpret_cast<const bf16x8*>(bpl + kb * 32);
  }

  // A (h_prev) element offset within a parity plane (u32 elements).
  const size_t aoff = (size_t)(mb * 32 + lr) * 1024 + kbase;

  // Epilogue mapping: one output element per thread.
  const int em = tid >> 4, en = tid & 15;
  const size_t eidx = (size_t)(mb * 32 + em) * 1024 + nb * 16 + en;

  unsigned int* my_arrive = cnt + (mb * 8 + (nb >> 3)) * 16;
  unsigned int* my_gate   = cnt + (mb * 8 + q) * 16;

  for (int t = 0; t < L_SEQ; ++t) {
    float* xpt = out + (size_t)t * BH;
    const float xpv = xpt[eidx];             // thread-private, prefetch early
    float hval;

    if (t > 0) {
      // Dataflow gate: wait for this wave's 8 producer WGs from step t-1.
      // Wave-level ordering: all 64 lanes stall until lane 0 exits the loop.
      if (l == 0) {
        const unsigned int tgt = 8u * (unsigned int)t;
        while (__hip_atomic_load(my_gate, __ATOMIC_RELAXED,
                                 __HIP_MEMORY_SCOPE_AGENT) < tgt) {
          __builtin_amdgcn_s_sleep(1);
        }
      }
      __builtin_amdgcn_sched_barrier(0);     // nothing drifts above the gate

      // Burst: 16 x dwordx4 sc0sc1 loads in flight, ONE drain.
      const uint* base0 = hb32 + (size_t)(((t - 1) & 1)) * BH + aoff;
      const uint* base1 = base0 + 16 * 1024;
      u32x4 pa[16];
#pragma unroll
      for (int kb = 0; kb < 4; ++kb) {
        ldg16_sc(pa[kb * 2 + 0],     base0 + kb * 32);
        ldg16_sc(pa[kb * 2 + 1],     base0 + kb * 32 + 4);
        ldg16_sc(pa[8 + kb * 2 + 0], base1 + kb * 32);
        ldg16_sc(pa[8 + kb * 2 + 1], base1 + kb * 32 + 4);
      }
      asm volatile("s_waitcnt vmcnt(0)" ::: "memory");
      __builtin_amdgcn_sched_barrier(0);     // rule #18: no consumer hoists

      f32x4 acc0 = {0.f, 0.f, 0.f, 0.f};
      f32x4 acc1 = {0.f, 0.f, 0.f, 0.f};
#pragma unroll
      for (int kb = 0; kb < 4; ++kb) {
        // Unpack packed u32 (hi | lo<<16) into bf16x8 hi/lo fragments.
        V8 h0, l0, h1, l1;
#pragma unroll
        for (int i = 0; i < 2; ++i) {
          u32x4 p0 = pa[kb * 2 + i];
          u32x4 p1 = pa[8 + kb * 2 + i];
          h0.w[i * 2 + 0] = (p0[0] & 0xffffu) | (p0[1] << 16);
          h0.w[i * 2 + 1] = (p0[2] & 0xffffu) | (p0[3] << 16);
          l0.w[i * 2 + 0] = (p0[0] >> 16) | (p0[1] & 0xffff0000u);
          l0.w[i * 2 + 1] = (p0[2] >> 16) | (p0[3] & 0xffff0000u);
          h1.w[i * 2 + 0] = (p1[0] & 0xffffu) | (p1[1] << 16);
          h1.w[i * 2 + 1] = (p1[2] & 0xffffu) | (p1[3] << 16);
          l1.w[i * 2 + 0] = (p1[0] >> 16) | (p1[1] & 0xffff0000u);
          l1.w[i * 2 + 1] = (p1[2] >> 16) | (p1[3] & 0xffff0000u);
        }
        acc0 = __builtin_amdgcn_mfma_f32_16x16x32_bf16(h0.b, vBh[kb], acc0, 0, 0, 0);
        acc1 = __builtin_amdgcn_mfma_f32_16x16x32_bf16(h1.b, vBh[kb], acc1, 0, 0, 0);
        acc0 = __builtin_amdgcn_mfma_f32_16x16x32_bf16(h0.b, vBl[kb], acc0, 0, 0, 0);
        acc1 = __builtin_amdgcn_mfma_f32_16x16x32_bf16(h1.b, vBl[kb], acc1, 0, 0, 0);
        acc0 = __builtin_amdgcn_mfma_f32_16x16x32_bf16(l0.b, vBh[kb], acc0, 0, 0, 0);
        acc1 = __builtin_amdgcn_mfma_f32_16x16x32_bf16(l1.b, vBh[kb], acc1, 0, 0, 0);
      }

      // Partials -> LDS. C/D layout: col = lane&15, row = (lane>>4)*4 + r.
#pragma unroll
      for (int r = 0; r < 4; ++r) {
        lds[q * 544 + (row0 + r) * 17 + lr]      = acc0[r];
        lds[q * 544 + (16 + row0 + r) * 17 + lr] = acc1[r];
      }
      __syncthreads();   // all waves' partials in LDS (=> all gates passed)

      float s = 0.f;
#pragma unroll
      for (int qq = 0; qq < 8; ++qq) s += lds[qq * 544 + em * 17 + en];
      hval = tanhf(s + xpv);
    } else {
      hval = tanhf(xpv);
    }

    // fp32 h in place (thread-private, ordinary cached store).
    xpt[eidx] = hval;
    // Packed bf16 hi/lo state: single u32 write-through store to L3.
    unsigned short hhi = f2bf(hval);
    unsigned short hlo = f2bf(hval - bf2f(hhi));
    stg4_sc(hb32 + (size_t)(t & 1) * BH + eidx,
            (uint)hhi | ((uint)hlo << 16));

    // Release: drain stores to L3, sync the WG, then publish arrival.
    asm volatile("s_waitcnt vmcnt(0)" ::: "memory");
    __syncthreads();   // also protects LDS against next step's overwrite
    if (tid == 0) {
      __hip_atomic_fetch_add(my_arrive, 1u, __ATOMIC_RELAXED,
                             __HIP_MEMORY_SCOPE_AGENT);
    }
  }
}

extern "C" void kernel_launch(void* const* d_in, const int* in_sizes, int n_in,
                              void* d_out, int out_size, void* d_ws, size_t ws_size,
                              hipStream_t stream) {
  const float* x  = (const float*)d_in[0];   // [512][128][512]
  const float* Wx = (const float*)d_in[1];   // [1024][512]
  const float* bx = (const float*)d_in[2];   // [1024]
  const float* Wh = (const float*)d_in[3];   // [1024][1024]
  float* out = (float*)d_out;                // [512][128][1024]
  unsigned short* ws = (unsigned short*)d_ws;

  unsigned short* whh = ws + WS_WHH;
  unsigned short* whl = ws + WS_WHL;
  unsigned short* wxh = ws + WS_WXH;
  unsigned short* wxl = ws + WS_WXL;
  uint* hb32          = (uint*)(ws + WS_HB); // [2][BH] packed
  unsigned int* cnt   = (unsigned int*)(ws + WS_CNT);

  split_kernel<<<dim3(2048), dim3(256), 0, stream>>>(Wh, Wx, ws, cnt);
  xproj_kernel<<<dim3(8192), dim3(256), 0, stream>>>(x, wxh, wxl, bx, out);
  rnn_persistent<<<dim3(256), dim3(512), 0, stream>>>(whh, whl, hb32, out, cnt);
}

// Round 8
// 3700.231 us; speedup vs baseline: 1.7910x; 1.2536x over previous
//
#include <hip/hip_runtime.h>
#include <math.h>

// RNN: L=512, B=128, D=512, H=1024, fp32 in/out.
//   xproj = x @ Wx^T + bx   (65536x1024x512 GEMM) -> written into d_out
//   h_t = tanh(xp_t + h_{t-1} @ Wh^T), in-place over d_out slices.
// Precision: split-bf16 (hi+lo) operands, 3 MFMAs per product => ~fp32 accuracy.
// Round 8 = round 7 resubmit (container died before bench; protocol audited
// deadlock-free) + bounded spin escape (~4M polls) so a true hang would
// surface as a failed validation instead of a dead container.
// Round 7 changes under test:
//  (1) per-WG FLAGS (plain sc0sc1 stores) replace fetch_add counters.
//  (2) h-state as separate hi/lo bf16 planes: A-burst feeds MFMA directly,
//      zero unpack VALU (round-6 u32 packing was a net loss).
//  (3) fast tanh via v_exp_f32/v_rcp_f32 (~5 VALU) replaces branchy libm.
//  (4) fp32 d_out store deferred past the flag publish (off release path).

#define L_SEQ 512
#define B_SZ  128
#define D_SZ  512
#define H_SZ  1024
#define BH    (B_SZ * H_SZ)   // 131072

typedef __bf16 bf16x8 __attribute__((ext_vector_type(8)));
typedef float  f32x4  __attribute__((ext_vector_type(4)));
typedef unsigned int uint;

union V8 { bf16x8 b; unsigned short u[8]; uint w[4]; };

__device__ __forceinline__ unsigned short f2bf(float f) {
  unsigned int u = __float_as_uint(f);
  u += 0x7FFFu + ((u >> 16) & 1u);   // round-to-nearest-even
  return (unsigned short)(u >> 16);
}
__device__ __forceinline__ float bf2f(unsigned short s) {
  return __uint_as_float(((unsigned int)s) << 16);
}

// tanh(x) = 1 - 2/(e^{2x}+1), exact formula; v_exp_f32 (2^x) + v_rcp_f32.
// Saturates correctly: x>>0 -> e=inf -> rcp=0 -> 1; x<<0 -> e=0 -> -1.
__device__ __forceinline__ float fast_tanh(float x) {
  float e;
  asm("v_exp_f32 %0, %1" : "=v"(e) : "v"(x * 2.885390081777927f));
  float r;
  asm("v_rcp_f32 %0, %1" : "=v"(r) : "v"(e + 1.0f));
  return 1.0f - 2.0f * r;
}

// 16B L1/L2-bypass load (reads the L3 coherence point). Plain load, NOT
// atomic: many stay in flight; we drain with one vmcnt(0).
__device__ __forceinline__ void ldg16_sc(bf16x8& d, const unsigned short* p) {
  asm volatile("global_load_dwordx4 %0, %1, off sc0 sc1"
               : "=v"(d) : "v"(p) : "memory");
}
// 2B / 4B write-through stores to the L3 coherence point.
__device__ __forceinline__ void stg2_sc(unsigned short* p, uint v) {
  asm volatile("global_store_short %0, %1, off sc0 sc1"
               :: "v"(p), "v"(v) : "memory");
}
__device__ __forceinline__ void stg4_sc(uint* p, uint v) {
  asm volatile("global_store_dword %0, %1, off sc0 sc1"
               :: "v"(p), "v"(v) : "memory");
}

// ---- d_ws layout (ushort elements unless noted) ----
#define WS_WHH 0            // [1024][1024]
#define WS_WHL 1048576      // [1024][1024]
#define WS_WXH 2097152      // [1024][512]
#define WS_WXL 2621440      // [1024][512]
#define WS_HB  3145728      // [2 parity][2 hi/lo][BH] ushort
#define WS_CNT 3670016      // flags: [4 mb][64 nb] u32 (zeroed per launch)

// Split fp32 weights into bf16 hi + bf16 lo(residual); zero flags.
__global__ void split_kernel(const float* __restrict__ Wh,
                             const float* __restrict__ Wx,
                             unsigned short* __restrict__ ws,
                             unsigned int* __restrict__ flags) {
  if (blockIdx.x == 0) {
    for (int i = threadIdx.x; i < 512; i += 256) flags[i] = 0u;
  }
  const int total = 1048576 + 524288;
  for (int i = blockIdx.x * blockDim.x + threadIdx.x; i < total;
       i += gridDim.x * blockDim.x) {
    const float* src; unsigned short *dh, *dl; int j;
    if (i < 1048576) { src = Wh; dh = ws + WS_WHH; dl = ws + WS_WHL; j = i; }
    else             { src = Wx; dh = ws + WS_WXH; dl = ws + WS_WXL; j = i - 1048576; }
    float v = src[j];
    unsigned short h = f2bf(v);
    dh[j] = h;
    dl[j] = f2bf(v - bf2f(h));
  }
}

// xproj: out[m][n] = sum_d x[m][d]*Wx[n][d] + bx[n]  (unchanged)
__global__ __launch_bounds__(256) void xproj_kernel(
    const float* __restrict__ x,             // [65536][512]
    const unsigned short* __restrict__ wxh,  // [1024][512]
    const unsigned short* __restrict__ wxl,
    const float* __restrict__ bx,            // [1024]
    float* __restrict__ out)                 // [65536][1024]
{
  const int bid = blockIdx.x;
  const int bn = bid & 15;
  const int bm = bid >> 4;
  const int tid = threadIdx.x;
  const int w = tid >> 6, l = tid & 63;
  const int wm = w & 1, wn = w >> 1;
  const int lr = l & 15, lk = (l >> 4) * 8;
  const int mbase = bm * 128 + wm * 64;
  const int nbase = bn * 64 + wn * 32;

  f32x4 acc[4][2] = {};

  for (int k0 = 0; k0 < 512; k0 += 32) {
    bf16x8 ah[4], al[4], bh[2], bl[2];
#pragma unroll
    for (int i = 0; i < 4; ++i) {
      const float* ap = x + (size_t)(mbase + i * 16 + lr) * 512 + k0 + lk;
      float4 v0 = *reinterpret_cast<const float4*>(ap);
      float4 v1 = *reinterpret_cast<const float4*>(ap + 4);
      float vv[8] = {v0.x, v0.y, v0.z, v0.w, v1.x, v1.y, v1.z, v1.w};
      V8 hh, ll;
#pragma unroll
      for (int e = 0; e < 8; ++e) {
        unsigned short hb = f2bf(vv[e]);
        hh.u[e] = hb;
        ll.u[e] = f2bf(vv[e] - bf2f(hb));
      }
      ah[i] = hh.b; al[i] = ll.b;
    }
#pragma unroll
    for (int j = 0; j < 2; ++j) {
      size_t boff = (size_t)(nbase + j * 16 + lr) * 512 + k0 + lk;
      bh[j] = *reinterpret_cast<const bf16x8*>(wxh + boff);
      bl[j] = *reinterpret_cast<const bf16x8*>(wxl + boff);
    }
#pragma unroll
    for (int i = 0; i < 4; ++i)
#pragma unroll
      for (int j = 0; j < 2; ++j) {
        acc[i][j] = __builtin_amdgcn_mfma_f32_16x16x32_bf16(ah[i], bh[j], acc[i][j], 0, 0, 0);
        acc[i][j] = __builtin_amdgcn_mfma_f32_16x16x32_bf16(ah[i], bl[j], acc[i][j], 0, 0, 0);
        acc[i][j] = __builtin_amdgcn_mfma_f32_16x16x32_bf16(al[i], bh[j], acc[i][j], 0, 0, 0);
      }
  }

#pragma unroll
  for (int j = 0; j < 2; ++j) {
    int n = nbase + j * 16 + lr;
    float bxv = bx[n];
#pragma unroll
    for (int i = 0; i < 4; ++i)
#pragma unroll
      for (int r = 0; r < 4; ++r) {
        int m = mbase + i * 16 + (l >> 4) * 4 + r;
        out[(size_t)m * 1024 + n] = acc[i][j][r] + bxv;
      }
  }
}

// Persistent recurrence (fence-free, flag-gated). 256 WGs x 512 threads.
// WG (mb,nb): rows [mb*32,+32) x cols [nb*16,+16), all 512 steps.
// Wave q owns K-slice [q*128,+128); Wh frags in registers throughout.
// Gate: wave q at step t waits flag[mb][8q+p] >= t for p=0..7 (its producers
// finished step t-1). Flags are plain sc0sc1 stores issued AFTER each WG's
// h-stores are drained to the coherence point (vmcnt(0) + __syncthreads), so
// flag>=t observed => h_{t-1} is L3-visible. Parity-plane reuse is race-free:
// a WG at step t implies ALL (mb,*) WGs completed step t-1 (its 8 waves'
// gates cover all 64 producer WGs), and their reads of plane t&1 (h_{t-2})
// preceded their step-(t-1) flags.
__global__ __launch_bounds__(512, 2) void rnn_persistent(
    const unsigned short* __restrict__ whh,  // [1024][1024]
    const unsigned short* __restrict__ whl,
    unsigned short* __restrict__ hb,         // [2 parity][2 hi/lo][BH]
    float* __restrict__ out,                 // [512][BH] (xproj in, h out)
    uint* __restrict__ flags)                // [4][64]
{
  __shared__ float lds[8 * 32 * 17];         // 17408 B, stride-17 pad
  const int wg = blockIdx.x;                 // 0..255
  const int xc = wg & 7, yy = wg >> 3;
  const int mb = xc & 3;
  const int nb = ((xc >> 2) << 5) + yy;      // 0..63
  const int tid = threadIdx.x;
  const int q = tid >> 6;                    // k-slice 0..7
  const int l = tid & 63;
  const int lr = l & 15, lk = (l >> 4) * 8;
  const int kbase = q * 128 + lk;
  const int row0 = (l >> 4) * 4;

  // Wh fragments: constant across all steps -> registers (8 frags = 32 VGPRs).
  const unsigned short* bph = whh + (size_t)(nb * 16 + lr) * 1024 + kbase;
  const unsigned short* bpl = whl + (size_t)(nb * 16 + lr) * 1024 + kbase;
  bf16x8 vBh[4], vBl[4];
#pragma unroll
  for (int kb = 0; kb < 4; ++kb) {
    vBh[kb] = *reinterpret_cast<const bf16x8*>(bph + kb * 32);
    vBl[kb] = *reinterpret_cast<const bf16x8*>(bpl + kb * 32);
  }

  // A (h_prev) offset within a hi/lo plane (ushort elements).
  const size_t aoff = (size_t)(mb * 32 + lr) * 1024 + kbase;
  const unsigned short* planeA0 = hb + aoff;            // parity 0 hi
  const unsigned short* planeA1 = hb + 2 * BH + aoff;   // parity 1 hi

  // Epilogue mapping: one output element per thread.
  const int em = tid >> 4, en = tid & 15;
  const size_t eidx = (size_t)(mb * 32 + em) * 1024 + nb * 16 + en;

  const uint* gate_ptr = flags + (mb << 6) + (q << 3) + (l & 7);
  uint* my_flag = flags + (mb << 6) + nb;

  for (int t = 0; t < L_SEQ; ++t) {
    float* xpt = out + (size_t)t * BH;
    const float xpv = xpt[eidx];             // prefetch; overlaps gate wait
    float hval;

    if (t > 0) {
      // Gate: poll 8 producer flags (coalesced per-lane load) until all >= t.
      // Bounded escape (~4M polls >> any legit wait): a protocol bug shows
      // up as failed validation, not a wedged GPU/container.
      const uint tgt = (uint)t;
      for (uint spin = 0; spin < (1u << 22); ++spin) {
        uint f;
        asm volatile("global_load_dword %0, %1, off sc0 sc1\n\t"
                     "s_waitcnt vmcnt(0)"
                     : "=v"(f) : "v"(gate_ptr) : "memory");
        if (__all((int)(f >= tgt))) break;
        __builtin_amdgcn_s_sleep(1);
      }
      __builtin_amdgcn_sched_barrier(0);     // nothing drifts above the gate

      // Burst: 16 x dwordx4 sc0sc1 loads in flight, ONE drain, no unpack.
      const unsigned short* ah = ((t - 1) & 1) ? planeA1 : planeA0;
      const unsigned short* al = ah + BH;
      bf16x8 vA0h[4], vA0l[4], vA1h[4], vA1l[4];
#pragma unroll
      for (int kb = 0; kb < 4; ++kb) {
        const int ko = kb * 32;
        ldg16_sc(vA0h[kb], ah + ko);
        ldg16_sc(vA0l[kb], al + ko);
        ldg16_sc(vA1h[kb], ah + 16 * 1024 + ko);
        ldg16_sc(vA1l[kb], al + 16 * 1024 + ko);
      }
      asm volatile("s_waitcnt vmcnt(0)" ::: "memory");
      __builtin_amdgcn_sched_barrier(0);     // rule #18: no consumer hoists

      f32x4 acc0 = {0.f, 0.f, 0.f, 0.f};
      f32x4 acc1 = {0.f, 0.f, 0.f, 0.f};
#pragma unroll
      for (int kb = 0; kb < 4; ++kb) {
        acc0 = __builtin_amdgcn_mfma_f32_16x16x32_bf16(vA0h[kb], vBh[kb], acc0, 0, 0, 0);
        acc1 = __builtin_amdgcn_mfma_f32_16x16x32_bf16(vA1h[kb], vBh[kb], acc1, 0, 0, 0);
        acc0 = __builtin_amdgcn_mfma_f32_16x16x32_bf16(vA0h[kb], vBl[kb], acc0, 0, 0, 0);
        acc1 = __builtin_amdgcn_mfma_f32_16x16x32_bf16(vA1h[kb], vBl[kb], acc1, 0, 0, 0);
        acc0 = __builtin_amdgcn_mfma_f32_16x16x32_bf16(vA0l[kb], vBh[kb], acc0, 0, 0, 0);
        acc1 = __builtin_amdgcn_mfma_f32_16x16x32_bf16(vA1l[kb], vBh[kb], acc1, 0, 0, 0);
      }

      // Partials -> LDS. C/D layout: col = lane&15, row = (lane>>4)*4 + r.
#pragma unroll
      for (int r = 0; r < 4; ++r) {
        lds[q * 544 + (row0 + r) * 17 + lr]      = acc0[r];
        lds[q * 544 + (16 + row0 + r) * 17 + lr] = acc1[r];
      }
      __syncthreads();   // all waves' partials in LDS (=> all gates passed)

      float s = 0.f;
#pragma unroll
      for (int qq = 0; qq < 8; ++qq) s += lds[qq * 544 + em * 17 + en];
      hval = fast_tanh(s + xpv);
    } else {
      hval = fast_tanh(xpv);
    }

    // Release path: bf16 hi/lo stores -> drain -> WG sync -> flag.
    unsigned short hhi = f2bf(hval);
    unsigned short hlo = f2bf(hval - bf2f(hhi));
    unsigned short* hcur = hb + (size_t)((t & 1) * 2) * BH;
    stg2_sc(hcur + eidx, (uint)hhi);
    stg2_sc(hcur + BH + eidx, (uint)hlo);
    asm volatile("s_waitcnt vmcnt(0)" ::: "memory");
    __syncthreads();   // also protects LDS against next step's overwrite
    if (tid == 0) stg4_sc(my_flag, (uint)(t + 1));

    // Off the critical path: fp32 h into d_out (never read by consumers).
    xpt[eidx] = hval;
  }
}

extern "C" void kernel_launch(void* const* d_in, const int* in_sizes, int n_in,
                              void* d_out, int out_size, void* d_ws, size_t ws_size,
                              hipStream_t stream) {
  const float* x  = (const float*)d_in[0];   // [512][128][512]
  const float* Wx = (const float*)d_in[1];   // [1024][512]
  const float* bx = (const float*)d_in[2];   // [1024]
  const float* Wh = (const float*)d_in[3];   // [1024][1024]
  float* out = (float*)d_out;                // [512][128][1024]
  unsigned short* ws = (unsigned short*)d_ws;

  unsigned short* whh = ws + WS_WHH;
  unsigned short* whl = ws + WS_WHL;
  unsigned short* wxh = ws + WS_WXH;
  unsigned short* wxl = ws + WS_WXL;
  unsigned short* hb  = ws + WS_HB;          // [2][2][BH]
  uint* flags         = (uint*)(ws + WS_CNT);

  split_kernel<<<dim3(2048), dim3(256), 0, stream>>>(Wh, Wx, ws, flags);
  xproj_kernel<<<dim3(8192), dim3(256), 0, stream>>>(x, wxh, wxl, bx, out);
  rnn_persistent<<<dim3(256), dim3(512), 0, stream>>>(whh, whl, hb, out, flags);
}